// Round 1
// baseline (429.293 us; speedup 1.0000x reference)
//
#include <hip/hip_runtime.h>
#include <hip/hip_bf16.h>
#include <math.h>

// Problem constants (from reference): B=16, T=128, U=32 (acts has U+1=33), V=1024
#define RB 16
#define RT 128
#define RU 32
#define RV 1024
#define NROWS (RB * RT * (RU + 1))   // 67584

// ---------------------------------------------------------------------------
// Kernel 1: per-(b,t,u) row logsumexp over V, then write
//   blank_ws[b,t,u]  = acts[b,t,u,blank]      - lse
//   emit_ws [b,t,u]  = acts[b,t,u,label[b,u]] - lse   (u < U only)
// One wave (64 lanes) per row; 4 x float4 per lane covers 1024 floats.
// ---------------------------------------------------------------------------
__global__ __launch_bounds__(256) void rnnt_lse_kernel(
    const float* __restrict__ acts,
    const int*   __restrict__ labels,
    const int*   __restrict__ label_lens,
    const int*   __restrict__ blank_p,
    float* __restrict__ blank_ws,
    float* __restrict__ emit_ws,
    int nrows, int n_labels)
{
    const int tid  = threadIdx.x;
    const int lane = tid & 63;
    const int wave = tid >> 6;
    const int row  = blockIdx.x * 4 + wave;
    if (row >= nrows) return;

    const float*  base = acts + (size_t)row * RV;
    const float4* b4   = (const float4*)base;

    float4 x0 = b4[lane];
    float4 x1 = b4[lane + 64];
    float4 x2 = b4[lane + 128];
    float4 x3 = b4[lane + 192];

    float m = fmaxf(fmaxf(fmaxf(x0.x, x0.y), fmaxf(x0.z, x0.w)),
                    fmaxf(fmaxf(x1.x, x1.y), fmaxf(x1.z, x1.w)));
    m = fmaxf(m, fmaxf(fmaxf(fmaxf(x2.x, x2.y), fmaxf(x2.z, x2.w)),
                       fmaxf(fmaxf(x3.x, x3.y), fmaxf(x3.z, x3.w))));
    #pragma unroll
    for (int off = 32; off > 0; off >>= 1)
        m = fmaxf(m, __shfl_xor(m, off));

    float s = expf(x0.x - m) + expf(x0.y - m) + expf(x0.z - m) + expf(x0.w - m)
            + expf(x1.x - m) + expf(x1.y - m) + expf(x1.z - m) + expf(x1.w - m)
            + expf(x2.x - m) + expf(x2.y - m) + expf(x2.z - m) + expf(x2.w - m)
            + expf(x3.x - m) + expf(x3.y - m) + expf(x3.z - m) + expf(x3.w - m);
    #pragma unroll
    for (int off = 32; off > 0; off >>= 1)
        s += __shfl_xor(s, off);

    if (lane == 0) {
        const float lse = m + logf(s);
        const int u  = row % (RU + 1);
        const int rt = row / (RU + 1);
        const int t  = rt % RT;
        const int b  = rt / RT;
        const int blank = blank_p[0];
        blank_ws[row] = base[blank] - lse;
        if (u < RU) {
            int cum = 0;
            for (int j = 0; j < b; ++j) cum += label_lens[j];
            int idx = cum + u;
            idx = min(max(idx, 0), n_labels - 1);
            const int lab = labels[idx];
            emit_ws[((size_t)b * RT + t) * RU + u] = base[lab] - lse;
        }
    }
}

// ---------------------------------------------------------------------------
// Kernel 2: per-batch forward DP (anti-diagonal wavefront in one wave).
//   alpha[t][u] = logaddexp(alpha[t-1][u] + blank[t-1][u],
//                           alpha[t][u-1] + emit[t][u-1])
// LDS rows padded to 34 so the skewed access (lane stride 33 mod 32 = 1)
// is bank-conflict-free.
// ---------------------------------------------------------------------------
__global__ __launch_bounds__(256) void rnnt_dp_kernel(
    const float* __restrict__ blank_ws,
    const float* __restrict__ emit_ws,
    const int*   __restrict__ act_lens,
    const int*   __restrict__ label_lens,
    float* __restrict__ out)
{
    __shared__ float sb[RT * 34];   // blank, [t][u] u<33, padded
    __shared__ float se[RT * 34];   // emit,  [t][u] u<32, padded

    const int b   = blockIdx.x;
    const int tid = threadIdx.x;
    const float* gb = blank_ws + (size_t)b * RT * (RU + 1);
    const float* ge = emit_ws  + (size_t)b * RT * RU;

    for (int i = tid; i < RT * (RU + 1); i += 256) {
        int t = i / (RU + 1), u = i - t * (RU + 1);
        sb[t * 34 + u] = gb[i];
    }
    for (int i = tid; i < RT * RU; i += 256) {
        int t = i / RU, u = i - t * RU;
        se[t * 34 + u] = ge[i];
    }
    __syncthreads();

    if (tid < 64) {
        const int u  = tid;
        const int Tb = act_lens[b];
        const int Ub = label_lens[b];

        // alpha[0][u] = sum_{j<u} emit[0][j]  (exclusive prefix via shfl scan)
        float v = (u >= 1 && u <= RU) ? se[u - 1] : 0.0f;
        #pragma unroll
        for (int off = 1; off < 64; off <<= 1) {
            float n = __shfl_up(v, off);
            if (u >= off) v += n;
        }
        float A  = v;      // lane u holds alpha[t][u], skewed over iterations
        float ll = 0.0f;

        const int smax = (Tb - 1) + Ub;
        for (int s = 1; s <= smax; ++s) {
            const float left = __shfl_up(A, 1);   // alpha[t][u-1]
            const int t = s - u;
            if (t >= 1 && t <= Tb - 1 && u <= RU) {
                const float ab = A + sb[(t - 1) * 34 + u];
                float nv;
                if (u == 0) {
                    nv = ab;
                } else {
                    const float ae = left + se[t * 34 + (u - 1)];
                    const float mx = fmaxf(ab, ae);
                    nv = mx + log1pf(expf(fminf(ab, ae) - mx));
                }
                A = nv;
                if (t == Tb - 1 && u == Ub)
                    ll = A + sb[t * 34 + u];
            }
        }
        const float llb = __shfl(ll, Ub);
        if (u == 0) atomicAdd(out, -llb);
    }
}

extern "C" void kernel_launch(void* const* d_in, const int* in_sizes, int n_in,
                              void* d_out, int out_size, void* d_ws, size_t ws_size,
                              hipStream_t stream) {
    const float* acts       = (const float*)d_in[0];
    const int*   labels     = (const int*)d_in[1];
    const int*   act_lens   = (const int*)d_in[2];
    const int*   label_lens = (const int*)d_in[3];
    const int*   blank_p    = (const int*)d_in[4];
    float* out = (float*)d_out;

    const int n_labels = in_sizes[1];   // B*U = 512

    float* blank_ws = (float*)d_ws;                    // NROWS floats
    float* emit_ws  = blank_ws + NROWS;                // B*T*U floats

    hipMemsetAsync(out, 0, sizeof(float), stream);

    const int nrows = NROWS;
    const int grid1 = (nrows + 3) / 4;   // 4 waves (rows) per 256-thread block
    rnnt_lse_kernel<<<grid1, 256, 0, stream>>>(
        acts, labels, label_lens, blank_p, blank_ws, emit_ws, nrows, n_labels);

    rnnt_dp_kernel<<<RB, 256, 0, stream>>>(
        blank_ws, emit_ws, act_lens, label_lens, out);
}

// Round 2
// 406.603 us; speedup vs baseline: 1.0558x; 1.0558x over previous
//
#include <hip/hip_runtime.h>
#include <hip/hip_bf16.h>
#include <math.h>

// Problem constants (from reference): B=16, T=128, U=32 (acts has U+1=33), V=1024
#define RB 16
#define RT 128
#define RU 32
#define RV 1024
#define NROWS (RB * RT * (RU + 1))   // 67584

// ---------------------------------------------------------------------------
// Kernel 1: per-(b,t,u) row logsumexp over V, then write
//   blank_ws[b,t,u] = acts[b,t,u,blank]      - lse
//   emit_ws [b,t,u] = acts[b,t,u,label[b,u]] - lse   (u < U only)
// One wave (64 lanes) per row; 4 x float4 per lane covers 1024 floats.
// Rows with t >= T_b or u > U_b are never used by the DP -> early-exit
// before the HBM loads (cuts fetched bytes from 277 MB to ~160 MB).
// ---------------------------------------------------------------------------
__global__ __launch_bounds__(256) void rnnt_lse_kernel(
    const float* __restrict__ acts,
    const int*   __restrict__ labels,
    const int*   __restrict__ act_lens,
    const int*   __restrict__ label_lens,
    const int*   __restrict__ blank_p,
    float* __restrict__ blank_ws,
    float* __restrict__ emit_ws,
    int n_labels)
{
    const int tid  = threadIdx.x;
    const int lane = tid & 63;
    const int wave = tid >> 6;
    const int row  = blockIdx.x * 4 + wave;   // grid sized so row < NROWS

    // decode (b, t, u); RT=128 and RU+1=33
    const int u  = row % (RU + 1);
    const int rt = row / (RU + 1);
    const int t  = rt & (RT - 1);
    const int b  = rt >> 7;

    const int Tb = act_lens[b];
    const int Ub = label_lens[b];
    if (t >= Tb || u > Ub) return;     // row never consumed by the DP

    // cum[b] = sum_{j<b} label_lens[j] via 16-lane shfl prefix scan
    // (replaces a 16-deep dependent-load chain on lane 0)
    int pls = (lane < RB) ? label_lens[lane] : 0;
    #pragma unroll
    for (int off = 1; off < RB; off <<= 1) {
        int n = __shfl_up(pls, off);
        if (lane >= off) pls += n;
    }
    const int cum = (b == 0) ? 0 : __shfl(pls, b - 1);

    const float*  base = acts + (size_t)row * RV;
    const float4* b4   = (const float4*)base;

    float4 x0 = b4[lane];
    float4 x1 = b4[lane + 64];
    float4 x2 = b4[lane + 128];
    float4 x3 = b4[lane + 192];

    float m = fmaxf(fmaxf(fmaxf(x0.x, x0.y), fmaxf(x0.z, x0.w)),
                    fmaxf(fmaxf(x1.x, x1.y), fmaxf(x1.z, x1.w)));
    m = fmaxf(m, fmaxf(fmaxf(fmaxf(x2.x, x2.y), fmaxf(x2.z, x2.w)),
                       fmaxf(fmaxf(x3.x, x3.y), fmaxf(x3.z, x3.w))));
    #pragma unroll
    for (int off = 32; off > 0; off >>= 1)
        m = fmaxf(m, __shfl_xor(m, off));

    float s = __expf(x0.x - m) + __expf(x0.y - m) + __expf(x0.z - m) + __expf(x0.w - m)
            + __expf(x1.x - m) + __expf(x1.y - m) + __expf(x1.z - m) + __expf(x1.w - m)
            + __expf(x2.x - m) + __expf(x2.y - m) + __expf(x2.z - m) + __expf(x2.w - m)
            + __expf(x3.x - m) + __expf(x3.y - m) + __expf(x3.z - m) + __expf(x3.w - m);
    #pragma unroll
    for (int off = 32; off > 0; off >>= 1)
        s += __shfl_xor(s, off);

    if (lane == 0) {
        const float lse = m + __logf(s);
        const int blank = blank_p[0];
        blank_ws[row] = base[blank] - lse;
        if (u < RU) {
            int idx = cum + u;
            idx = min(max(idx, 0), n_labels - 1);
            const int lab = labels[idx];
            emit_ws[((size_t)b * RT + t) * RU + u] = base[lab] - lse;
        }
    }
}

// ---------------------------------------------------------------------------
// Kernel 2: per-batch forward DP (anti-diagonal wavefront in one wave).
//   alpha[t][u] = logaddexp(alpha[t-1][u] + blank[t-1][u],
//                           alpha[t][u-1] + emit[t][u-1])
// LDS rows padded to 34 so the skewed access (lane stride 33 mod 32 = 1)
// is bank-conflict-free. Cells beyond (T_b, U_b) hold harness poison
// (0xAAAAAAAA = -3e-13) but are provably never read by live lanes.
// ---------------------------------------------------------------------------
__global__ __launch_bounds__(256) void rnnt_dp_kernel(
    const float* __restrict__ blank_ws,
    const float* __restrict__ emit_ws,
    const int*   __restrict__ act_lens,
    const int*   __restrict__ label_lens,
    float* __restrict__ out)
{
    __shared__ float sb[RT * 34];   // blank, [t][u] u<33, padded
    __shared__ float se[RT * 34];   // emit,  [t][u] u<32, padded

    const int b   = blockIdx.x;
    const int tid = threadIdx.x;
    const float* gb = blank_ws + (size_t)b * RT * (RU + 1);
    const float* ge = emit_ws  + (size_t)b * RT * RU;

    for (int i = tid; i < RT * (RU + 1); i += 256) {
        int t = i / (RU + 1), u = i - t * (RU + 1);
        sb[t * 34 + u] = gb[i];
    }
    for (int i = tid; i < RT * RU; i += 256) {
        int t = i / RU, u = i - t * RU;
        se[t * 34 + u] = ge[i];
    }
    __syncthreads();

    if (tid < 64) {
        const int u  = tid;
        const int Tb = act_lens[b];
        const int Ub = label_lens[b];

        // alpha[0][u] = sum_{j<u} emit[0][j]  (exclusive prefix via shfl scan)
        float v = (u >= 1 && u <= RU) ? se[u - 1] : 0.0f;
        #pragma unroll
        for (int off = 1; off < 64; off <<= 1) {
            float n = __shfl_up(v, off);
            if (u >= off) v += n;
        }
        float A  = v;      // lane u holds alpha[t][u], skewed over iterations
        float ll = 0.0f;

        const int smax = (Tb - 1) + Ub;
        for (int s = 1; s <= smax; ++s) {
            const float left = __shfl_up(A, 1);   // alpha[t][u-1]
            const int t = s - u;
            if (t >= 1 && t <= Tb - 1 && u <= RU) {
                const float ab = A + sb[(t - 1) * 34 + u];
                float nv;
                if (u == 0) {
                    nv = ab;
                } else {
                    const float ae = left + se[t * 34 + (u - 1)];
                    const float mx = fmaxf(ab, ae);
                    nv = mx + log1pf(__expf(fminf(ab, ae) - mx));
                }
                A = nv;
                if (t == Tb - 1 && u == Ub)
                    ll = A + sb[t * 34 + u];
            }
        }
        const float llb = __shfl(ll, Ub);
        if (u == 0) atomicAdd(out, -llb);
    }
}

extern "C" void kernel_launch(void* const* d_in, const int* in_sizes, int n_in,
                              void* d_out, int out_size, void* d_ws, size_t ws_size,
                              hipStream_t stream) {
    const float* acts       = (const float*)d_in[0];
    const int*   labels     = (const int*)d_in[1];
    const int*   act_lens   = (const int*)d_in[2];
    const int*   label_lens = (const int*)d_in[3];
    const int*   blank_p    = (const int*)d_in[4];
    float* out = (float*)d_out;

    const int n_labels = in_sizes[1];   // B*U = 512

    float* blank_ws = (float*)d_ws;                    // NROWS floats
    float* emit_ws  = blank_ws + NROWS;                // B*T*U floats

    hipMemsetAsync(out, 0, sizeof(float), stream);

    const int grid1 = NROWS / 4;   // 4 waves (rows) per 256-thread block
    rnnt_lse_kernel<<<grid1, 256, 0, stream>>>(
        acts, labels, act_lens, label_lens, blank_p, blank_ws, emit_ws, n_labels);

    rnnt_dp_kernel<<<RB, 256, 0, stream>>>(
        blank_ws, emit_ws, act_lens, label_lens, out);
}